// Round 1
// baseline (575.897 us; speedup 1.0000x reference)
//
#include <hip/hip_runtime.h>

// Problem constants from the reference
#define V_ 100000
#define D_ 300
#define B_ 64
#define L_ 256
#define C_ 10
#define I_ 6
#define NPOS (B_ * L_)          // 16384 positions
#define NROWS (1 + C_ + C_ + I_) // 27 rows staged per position
#define NDOTS (C_ + C_ * I_)     // 10 + 60 = 70 dot products
#define ROW_F4 (D_ / 4)          // 75 float4 per row (300 floats, 1200B, 16B aligned)

// One block per (b,l) position. 256 threads = 4 waves.
__global__ __launch_bounds__(256) void hg2vec_pos_kernel(
    const int* __restrict__ pos_u, const int* __restrict__ pos_v,
    const int* __restrict__ info_v,
    const float* __restrict__ W_in, const float* __restrict__ W_out,
    const float* __restrict__ context_mask, const float* __restrict__ sig_mask,
    const float* __restrict__ score_mask, float* __restrict__ partial)
{
    const int p = blockIdx.x;
    const int tid = threadIdx.x;

    // Row layout in LDS: [0]=u (W_out[pos_u]); [1..10]=ctx_in (W_in, masked);
    // [11..20]=ctx_out (W_out); [21..26]=info_in (W_in)
    __shared__ __align__(16) float s_rows[NROWS * D_];
    __shared__ const float* s_src[NROWS];
    __shared__ float s_scale[NROWS];
    __shared__ float s_sig[I_];
    __shared__ float s_smask[I_];

    if (tid < NROWS) {
        const float* src;
        float scale = 1.0f;
        if (tid == 0) {
            src = W_out + (size_t)pos_u[p] * D_;
        } else if (tid < 1 + C_) {
            int c = tid - 1;
            src = W_in + (size_t)pos_v[p * C_ + c] * D_;
            scale = context_mask[c];
        } else if (tid < 1 + 2 * C_) {
            int c = tid - 1 - C_;
            src = W_out + (size_t)pos_v[p * C_ + c] * D_;
        } else {
            int i = tid - 1 - 2 * C_;
            src = W_in + (size_t)info_v[p * I_ + i] * D_;
        }
        s_src[tid] = src;
        s_scale[tid] = scale;
    }
    if (tid >= 32 && tid < 32 + I_) {
        s_sig[tid - 32] = sig_mask[tid - 32];
        s_smask[tid - 32] = score_mask[tid - 32];
    }
    __syncthreads();

    // Stage 27 rows into LDS, vectorized float4 (27*75 = 2025 float4, ~8 iters)
    for (int idx = tid; idx < NROWS * ROW_F4; idx += 256) {
        int r = idx / ROW_F4;
        int q = idx - r * ROW_F4;
        float4 v = ((const float4*)s_src[r])[q];
        float sc = s_scale[r];
        float4* dst = (float4*)(s_rows + r * D_);
        dst[q] = make_float4(v.x * sc, v.y * sc, v.z * sc, v.w * sc);
    }
    __syncthreads();

    const int wave = tid >> 6;
    const int lane = tid & 63;
    float acc = 0.0f;

    // 70 dots distributed over 4 waves
    for (int d = wave; d < NDOTS; d += 4) {
        const float* a;
        const float* b;
        int ii = -1;
        if (d < C_) {
            a = s_rows;                  // u
            b = s_rows + (1 + d) * D_;   // ctx_in (masked)
        } else {
            int d2 = d - C_;
            int c = d2 / I_;
            ii = d2 - c * I_;
            a = s_rows + (1 + C_ + c) * D_;       // ctx_out
            b = s_rows + (1 + 2 * C_ + ii) * D_;  // info_in
        }
        float dot = 0.0f;
        for (int k = lane; k < D_; k += 64) dot += a[k] * b[k];
#pragma unroll
        for (int off = 32; off; off >>= 1) dot += __shfl_xor(dot, off, 64);
        if (lane == 0) {
            float x = fminf(fmaxf(dot, -10.0f), 10.0f);
            if (ii >= 0) {
                x *= s_sig[ii];
                acc += log1pf(expf(-x)) * s_smask[ii];   // -log_sigmoid * score_mask
            } else {
                acc += log1pf(expf(-x));                 // -log_sigmoid
            }
        }
    }

    __shared__ float s_wacc[4];
    if (lane == 0) s_wacc[wave] = acc;
    __syncthreads();
    if (tid == 0) partial[p] = s_wacc[0] + s_wacc[1] + s_wacc[2] + s_wacc[3];
}

// Single-block final reduction of 16384 partials -> out[0]
__global__ __launch_bounds__(256) void hg2vec_reduce_kernel(
    const float* __restrict__ partial, float* __restrict__ out, int n)
{
    float acc = 0.0f;
    for (int i = threadIdx.x; i < n; i += 256) acc += partial[i];
#pragma unroll
    for (int off = 32; off; off >>= 1) acc += __shfl_xor(acc, off, 64);
    __shared__ float s[4];
    if ((threadIdx.x & 63) == 0) s[threadIdx.x >> 6] = acc;
    __syncthreads();
    if (threadIdx.x == 0) out[0] = s[0] + s[1] + s[2] + s[3];
}

extern "C" void kernel_launch(void* const* d_in, const int* in_sizes, int n_in,
                              void* d_out, int out_size, void* d_ws, size_t ws_size,
                              hipStream_t stream) {
    const int* pos_u = (const int*)d_in[0];
    const int* pos_v = (const int*)d_in[1];
    const int* info_v = (const int*)d_in[2];
    const float* W_in = (const float*)d_in[3];
    const float* W_out = (const float*)d_in[4];
    const float* context_mask = (const float*)d_in[5];
    const float* sig_mask = (const float*)d_in[6];
    const float* score_mask = (const float*)d_in[7];
    float* out = (float*)d_out;
    float* partial = (float*)d_ws;   // NPOS floats = 64 KB scratch

    hg2vec_pos_kernel<<<NPOS, 256, 0, stream>>>(
        pos_u, pos_v, info_v, W_in, W_out,
        context_mask, sig_mask, score_mask, partial);
    hg2vec_reduce_kernel<<<1, 256, 0, stream>>>(partial, out, NPOS);
}

// Round 2
// 286.602 us; speedup vs baseline: 2.0094x; 2.0094x over previous
//
#include <hip/hip_runtime.h>

#define D_ 300
#define C_ 10
#define I_ 6
#define NPOS 16384
#define PPB 4                 // positions (one wave each) per block
#define NBLK (NPOS / PPB)     // 4096 blocks
#define CHUNK 35              // dots per reduction chunk (5 c-groups x 7 dots)

__device__ __forceinline__ float neg_log_sigmoid(float x) {
    // -log_sigmoid(x) = log(1 + exp(-x)); x in [-10,10] so fp32 is safe
    return __logf(1.0f + __expf(-x));
}

// One wave per position. Rows live in registers, lane l holds k = l + 64*j.
__global__ __launch_bounds__(256, 4) void hg2vec_pos_kernel(
    const int* __restrict__ pos_u, const int* __restrict__ pos_v,
    const int* __restrict__ info_v,
    const float* __restrict__ W_in, const float* __restrict__ W_out,
    const float* __restrict__ context_mask, const float* __restrict__ sig_mask,
    const float* __restrict__ score_mask, float* __restrict__ partial)
{
    const int wave = threadIdx.x >> 6;
    const int lane = threadIdx.x & 63;
    const int p = blockIdx.x * PPB + wave;

    __shared__ float s_red[PPB][CHUNK][65];   // +1 pad column: 2-way bank alias only
    __shared__ float s_wsum[PPB];

    // Wave-uniform indices -> SGPRs so every row load is saddr + shared lane offset
    const int su = __builtin_amdgcn_readfirstlane(pos_u[p]);
    int scv[C_], siv[I_];
#pragma unroll
    for (int c = 0; c < C_; ++c) scv[c] = __builtin_amdgcn_readfirstlane(pos_v[p * C_ + c]);
#pragma unroll
    for (int i = 0; i < I_; ++i) siv[i] = __builtin_amdgcn_readfirstlane(info_v[p * I_ + i]);

    // Tail handling: j=4 covers k = lane+256, valid only for lane < 44.
    const int k4 = lane + 256;
    const float okf = (k4 < D_) ? 1.0f : 0.0f;
    const int k4c = (k4 < D_) ? k4 : lane;    // clamped safe address

    // Target row u = W_out[su] (tail zeroed)
    const float* ur = W_out + (size_t)su * D_;
    float u0 = ur[lane], u1 = ur[lane + 64], u2 = ur[lane + 128], u3 = ur[lane + 192];
    float u4 = ur[k4c] * okf;

    // Info rows W_in[siv[i]], kept resident (tail zeroed)
    float ii0[I_], ii1[I_], ii2[I_], ii3[I_], ii4[I_];
#pragma unroll
    for (int i = 0; i < I_; ++i) {
        const float* r = W_in + (size_t)siv[i] * D_;
        ii0[i] = r[lane];       ii1[i] = r[lane + 64];
        ii2[i] = r[lane + 128]; ii3[i] = r[lane + 192];
        ii4[i] = r[k4c] * okf;
    }

    float acc = 0.0f;

#pragma unroll
    for (int chunk = 0; chunk < 2; ++chunk) {
        float part[CHUNK];
#pragma unroll
        for (int cc = 0; cc < 5; ++cc) {
            const int c = chunk * 5 + cc;
            const float* cir = W_in  + (size_t)scv[c] * D_;
            const float* cor = W_out + (size_t)scv[c] * D_;
            float a0 = cir[lane], a1 = cir[lane + 64], a2 = cir[lane + 128],
                  a3 = cir[lane + 192], a4 = cir[k4c];          // a4 garbage * u4==0 -> ok
            float b0 = cor[lane], b1 = cor[lane + 64], b2 = cor[lane + 128],
                  b3 = cor[lane + 192], b4 = cor[k4c];          // b4 garbage * ii4==0 -> ok
            part[cc * 7] = u0 * a0 + u1 * a1 + u2 * a2 + u3 * a3 + u4 * a4;
#pragma unroll
            for (int i = 0; i < I_; ++i)
                part[cc * 7 + 1 + i] =
                    b0 * ii0[i] + b1 * ii1[i] + b2 * ii2[i] + b3 * ii3[i] + b4 * ii4[i];
        }

        __syncthreads();   // protects previous chunk's reads before buffer reuse
#pragma unroll
        for (int d = 0; d < CHUNK; ++d) s_red[wave][d][lane] = part[d];
        __syncthreads();

        if (lane < CHUNK) {
            // 4-way ILP serial sum of 64 lane-partials for this dot
            float s0 = 0, s1 = 0, s2 = 0, s3 = 0;
#pragma unroll
            for (int l = 0; l < 64; l += 4) {
                s0 += s_red[wave][lane][l + 0];
                s1 += s_red[wave][lane][l + 1];
                s2 += s_red[wave][lane][l + 2];
                s3 += s_red[wave][lane][l + 3];
            }
            float dot = (s0 + s1) + (s2 + s3);
            const int cc = lane / 7;
            const int t  = lane - cc * 7;
            const int c  = chunk * 5 + cc;
            float term;
            if (t == 0) {
                // score = dot(u, mask*cin) = mask*dot; then clip, then -logsig
                float x = dot * context_mask[c];
                x = fminf(fmaxf(x, -10.0f), 10.0f);
                term = neg_log_sigmoid(x);
            } else {
                const int i = t - 1;
                float x = fminf(fmaxf(dot, -10.0f), 10.0f) * sig_mask[i];
                term = neg_log_sigmoid(x) * score_mask[i];
            }
            acc += term;
        }
    }

    // per-wave total (lanes >= 35 contribute 0)
#pragma unroll
    for (int off = 32; off; off >>= 1) acc += __shfl_xor(acc, off, 64);
    if (lane == 0) s_wsum[wave] = acc;
    __syncthreads();
    if (threadIdx.x == 0)
        partial[blockIdx.x] = s_wsum[0] + s_wsum[1] + s_wsum[2] + s_wsum[3];
}

// Single block, 1024 threads: 4096 partials = 1024 float4, one per thread.
__global__ __launch_bounds__(1024) void hg2vec_reduce_kernel(
    const float* __restrict__ partial, float* __restrict__ out)
{
    float4 v = ((const float4*)partial)[threadIdx.x];
    float a = (v.x + v.y) + (v.z + v.w);
#pragma unroll
    for (int off = 32; off; off >>= 1) a += __shfl_xor(a, off, 64);
    __shared__ float s[16];
    if ((threadIdx.x & 63) == 0) s[threadIdx.x >> 6] = a;
    __syncthreads();
    if (threadIdx.x == 0) {
        float t = 0;
#pragma unroll
        for (int i = 0; i < 16; ++i) t += s[i];
        out[0] = t;
    }
}

extern "C" void kernel_launch(void* const* d_in, const int* in_sizes, int n_in,
                              void* d_out, int out_size, void* d_ws, size_t ws_size,
                              hipStream_t stream) {
    const int* pos_u = (const int*)d_in[0];
    const int* pos_v = (const int*)d_in[1];
    const int* info_v = (const int*)d_in[2];
    const float* W_in = (const float*)d_in[3];
    const float* W_out = (const float*)d_in[4];
    const float* context_mask = (const float*)d_in[5];
    const float* sig_mask = (const float*)d_in[6];
    const float* score_mask = (const float*)d_in[7];
    float* out = (float*)d_out;
    float* partial = (float*)d_ws;   // NBLK floats = 16 KB scratch

    hg2vec_pos_kernel<<<NBLK, 256, 0, stream>>>(
        pos_u, pos_v, info_v, W_in, W_out,
        context_mask, sig_mask, score_mask, partial);
    hg2vec_reduce_kernel<<<1, 1024, 0, stream>>>(partial, out);
}